// Round 18
// baseline (165.654 us; speedup 1.0000x reference)
//
#include <hip/hip_runtime.h>
#include <hip/hip_bf16.h>
#include <math.h>

typedef short bf16x8 __attribute__((ext_vector_type(8)));
typedef float f32x4  __attribute__((ext_vector_type(4)));

constexpr int   H     = 256;
constexpr int   KNB   = 32;
constexpr int   TPB   = 512;     // 8 waves/block
constexpr int   GC    = 16;      // bin-grid cells per dim
constexpr float HINV  = 1.6f;    // GC / 10.0
constexpr float HCEL  = 0.625f;  // 10.0 / GC
constexpr int   SLOTS = 32;      // slots per cell (avg fill ~12.2; overflow spills)
constexpr int   OCAP  = 256;     // overflow list capacity
constexpr int   CAP   = 1024;    // candidate buffer (expected ~400)

__device__ __forceinline__ ushort f2bf(float x) {
    unsigned u = __float_as_uint(x);
    u += 0x7FFF + ((u >> 16) & 1);
    return (ushort)(u >> 16);
}

__device__ __forceinline__ float gelu_fast(float x) {
    float u = 0.7978845608028654f * (x + 0.044715f * x * x * x);
    float t = exp2f(-2.885390081777927f * u);
    return x / (1.0f + t);
}

__device__ __forceinline__ int cell_of(float x, float y, float z) {
    int cx = min(GC - 1, max(0, (int)(x * HINV)));
    int cy = min(GC - 1, max(0, (int)(y * HINV)));
    int cz = min(GC - 1, max(0, (int)(z * HINV)));
    return (cz * GC + cy) * GC + cx;
}

// ---- prep: W1t (b<64), Wpt (64..191), W2t (192..255), vector scatter (256..) ----
__global__ __launch_bounds__(256)
void prep(const float* __restrict__ W1, const float* __restrict__ Wp,
          const float* __restrict__ W2, const float* __restrict__ pos, int N,
          ushort* __restrict__ W1t, ushort* __restrict__ Wpt,
          ushort* __restrict__ W2t, float4* __restrict__ pos4s,
          int* __restrict__ origidx, int* __restrict__ cellcnt,
          int* __restrict__ ovfidx, float4* __restrict__ ovfpos) {
    const int b = blockIdx.x;
    if (b < 64) {
        __shared__ float tile[32][33];
        const int ti = b >> 3, tj = b & 7;
        const int r  = threadIdx.x >> 5, c = threadIdx.x & 31;
#pragma unroll
        for (int rr = r; rr < 32; rr += 8)
            tile[rr][c] = W1[(ti * 32 + rr) * H + tj * 32 + c];
        __syncthreads();
#pragma unroll
        for (int rr = r; rr < 32; rr += 8)
            W1t[(tj * 32 + rr) * H + ti * 32 + c] = f2bf(tile[c][rr]);
    } else if (b < 192) {
        __shared__ float tile[32][33];
        const int b2 = b - 64;
        const int ti = b2 >> 3, tj = b2 & 7;
        const int r  = threadIdx.x >> 5, c = threadIdx.x & 31;
#pragma unroll
        for (int rr = r; rr < 32; rr += 8)
            tile[rr][c] = Wp[(ti * 32 + rr) * H + tj * 32 + c];
        __syncthreads();
#pragma unroll
        for (int rr = r; rr < 32; rr += 8)
            Wpt[(tj * 32 + rr) * (2 * H) + ti * 32 + c] = f2bf(tile[c][rr]);
    } else if (b < 256) {
        __shared__ float tile[32][33];
        const int b2 = b - 192;
        const int ti = b2 >> 3, tj = b2 & 7;
        const int r  = threadIdx.x >> 5, c = threadIdx.x & 31;
#pragma unroll
        for (int rr = r; rr < 32; rr += 8)
            tile[rr][c] = W2[(ti * 32 + rr) * H + tj * 32 + c];
        __syncthreads();
#pragma unroll
        for (int rr = r; rr < 32; rr += 8)
            W2t[(tj * 32 + rr) * H + ti * 32 + c] = f2bf(tile[c][rr]);
    } else {
        const int sb = b - 256;
        const int base = sb * 1024;
        const int t = threadIdx.x;
        auto scat = [&](float x, float y, float z, int i) {
            float4 P = make_float4(x, y, z, 0.f);
            int c = cell_of(x, y, z);
            int slot = atomicAdd(&cellcnt[c], 1);
            if (slot < SLOTS) {
                pos4s[c * SLOTS + slot] = P;
                origidx[c * SLOTS + slot] = i;
            } else {
                int o = atomicAdd(&cellcnt[4096], 1);
                if (o < OCAP) { ovfpos[o] = P; ovfidx[o] = i; }
            }
        };
        if (base + 1024 <= N) {
            const float4* p4 = (const float4*)(pos + (size_t)base * 3);
            float4 f0 = p4[3 * t + 0];
            float4 f1 = p4[3 * t + 1];
            float4 f2 = p4[3 * t + 2];
            const int ib = base + 4 * t;
            scat(f0.x, f0.y, f0.z, ib + 0);
            scat(f0.w, f1.x, f1.y, ib + 1);
            scat(f1.z, f1.w, f2.x, ib + 2);
            scat(f2.y, f2.z, f2.w, ib + 3);
        } else {
            for (int i = base + t; i < N; i += 256)
                scat(pos[3 * i], pos[3 * i + 1], pos[3 * i + 2], i);
        }
    }
}

// ---- fused: single-phase select (cell-tau -> dense ball gather -> rank) ->
//      embed -> MFMA GEMM1 -> gelu/mean -> hbB (bf16); supE -> supEB ----
__global__ __launch_bounds__(TPB, 8)
void fused_knn_mlp(const float* __restrict__ pos,
                   const float4* __restrict__ pos4s,
                   const int* __restrict__ origidx,
                   const int* __restrict__ cellcnt,
                   const int* __restrict__ ovfidx, const float4* __restrict__ ovfpos,
                   const int* __restrict__ supidx,
                   const ushort* __restrict__ W1t, const float* __restrict__ b1,
                   ushort* __restrict__ supEB, ushort* __restrict__ hbB)
{
    // 24.5 KB pool: amaxd[128]@0 | acnt[128]@512 | ccell[256]@1024 | ccnt[256]@2048 |
    //   cpre[256]@3072 | d2buf[1024]@4096 | obuf[1024]@8192 | pxb[1024]@12288 |
    //   pyb[1024]@16384 | pzb[1024]@20480
    // mlp: msg bf16[32][256]@0 (16 KB, XOR-swizzled)
    __shared__ __align__(16) char pool[24576];
    float* amaxd = (float*)pool;
    int*   acnt  = (int*)(pool + 512);
    int*   ccell = (int*)(pool + 1024);
    int*   ccnt  = (int*)(pool + 2048);
    int*   cpre  = (int*)(pool + 3072);
    float* d2buf = (float*)(pool + 4096);
    int*   obuf  = (int*)(pool + 8192);
    float* pxb   = (float*)(pool + 12288);
    float* pyb   = (float*)(pool + 16384);
    float* pzb   = (float*)(pool + 20480);
    ushort* msg  = (ushort*)pool;

    __shared__ float rf[KNB][5];
    __shared__ int   selo[KNB];
    __shared__ int   wsum[4];
    __shared__ float tau2_sh;
    __shared__ int   ncl;

    const int s    = blockIdx.x;
    const int t    = threadIdx.x;
    const int lane = t & 63;
    const int w    = t >> 6;       // wave 0..7

    const int sidx = supidx[s];
    const float sx = pos[3 * sidx], sy = pos[3 * sidx + 1], sz = pos[3 * sidx + 2];

    constexpr float L2_10000 = 13.287712379549449f;

    if (t == 0) { ncl = 0; tau2_sh = 301.f; }

    // ---- stage A: window cellcnt loads (latency hidden by supE embed) ----
    const int scx = min(GC - 1, max(0, (int)(sx * HINV)));
    const int scy = min(GC - 1, max(0, (int)(sy * HINV)));
    const int scz = min(GC - 1, max(0, (int)(sz * HINV)));
    const int ax0 = max(0, scx - 2), ax1 = min(GC - 1, scx + 2);
    const int ay0 = max(0, scy - 2), ay1 = min(GC - 1, scy + 2);
    const int az0 = max(0, scz - 2), az1 = min(GC - 1, scz + 2);
    const int anx = ax1 - ax0 + 1, any_ = ay1 - ay0 + 1, anz = az1 - az0 + 1;
    const int an  = anx * any_ * anz;    // <= 125
    if (t < an) {
        int ci = t;
        int X = ax0 + ci % anx, rem = ci / anx;
        int Y = ay0 + rem % any_, Z = az0 + rem / any_;
        int cell = (Z * GC + Y) * GC + X;
        acnt[ci] = min(cellcnt[cell], SLOTS);
        float lx = X * HCEL, ly = Y * HCEL, lz = Z * HCEL;
        float mx = fmaxf(fabsf(sx - lx), fabsf(lx + HCEL - sx));
        float my = fmaxf(fabsf(sy - ly), fabsf(ly + HCEL - sy));
        float mz = fmaxf(fabsf(sz - lz), fabsf(lz + HCEL - sz));
        amaxd[ci] = mx * mx + my * my + mz * mz;
    }

    // supE embed -> supEB[s][0..255] (bf16)
    if (t < 256) {
        float se = 0.f;
        if (t < 252) {
            int c  = t / 84;
            int rr = t - c * 84;
            int f  = (rr < 42) ? rr : rr - 42;
            float coord = (c == 0) ? sx : ((c == 1) ? sy : sz);
            float ang = coord * exp2f(-(float)f * (L2_10000 / 42.f));
            se = (rr < 42) ? __sinf(ang) : __cosf(ang);
        }
        supEB[s * H + t] = f2bf(se);
    }
    __syncthreads();
    // smallest amax whose cumulative count reaches 32 => >=32 pts within tau
    if (t < an) {
        int ci = t;
        float myv = amaxd[ci];
        int Sc = 0;
        for (int j = 0; j < an; j++) {
            bool less = (amaxd[j] < myv) || (amaxd[j] == myv && j < ci);
            Sc += less ? acnt[j] : 0;
        }
        if (Sc < KNB && KNB <= Sc + acnt[ci]) tau2_sh = myv;
    }
    __syncthreads();
    const float tau2 = tau2_sh;
    const float R2 = tau2 + 1e-3f;
    const float R  = sqrtf(R2);

    // ---- stage B: list ALL ball cells (mind2 <= R2); guarantees superset:
    //      any point outside these cells has d2 > R2 >= d32 ----
    const int bx0 = max(0, (int)floorf((sx - R) * HINV));
    const int bx1 = min(GC - 1, (int)floorf((sx + R) * HINV));
    const int by0 = max(0, (int)floorf((sy - R) * HINV));
    const int by1 = min(GC - 1, (int)floorf((sy + R) * HINV));
    const int bz0 = max(0, (int)floorf((sz - R) * HINV));
    const int bz1 = min(GC - 1, (int)floorf((sz + R) * HINV));
    const bool inwin = (bx0 >= ax0 && bx1 <= ax1 && by0 >= ay0 && by1 <= ay1 &&
                        bz0 >= az0 && bz1 <= az1);
    if (inwin) {
        // common: ball cells within loaded window -> no global reloads
        if (t < an) {
            int ci = t;
            int cn = acnt[ci];
            if (cn > 0) {
                int X = ax0 + ci % anx, rem = ci / anx;
                int Y = ay0 + rem % any_, Z = az0 + rem / any_;
                float lx = X * HCEL, ly = Y * HCEL, lz = Z * HCEL;
                float ddx = fmaxf(fmaxf(lx - sx, sx - (lx + HCEL)), 0.f);
                float ddy = fmaxf(fmaxf(ly - sy, sy - (ly + HCEL)), 0.f);
                float ddz = fmaxf(fmaxf(lz - sz, sz - (lz + HCEL)), 0.f);
                if (ddx * ddx + ddy * ddy + ddz * ddz <= R2) {
                    int cell = (Z * GC + Y) * GC + X;
                    int sl = atomicAdd(&ncl, 1);
                    if (sl < 256) { ccell[sl] = cell; ccnt[sl] = cn; }
                }
            }
        }
    } else {
        // rare: ball exceeds window -> reload path
        const int nbx = bx1 - bx0 + 1, nby = by1 - by0 + 1, nbz = bz1 - bz0 + 1;
        const int ncb = nbx * nby * nbz;
        for (int ci = t; ci < ncb; ci += TPB) {
            int X = bx0 + ci % nbx, rem = ci / nbx;
            int Y = by0 + rem % nby, Z = bz0 + rem / nby;
            float lx = X * HCEL, ly = Y * HCEL, lz = Z * HCEL;
            float ddx = fmaxf(fmaxf(lx - sx, sx - (lx + HCEL)), 0.f);
            float ddy = fmaxf(fmaxf(ly - sy, sy - (ly + HCEL)), 0.f);
            float ddz = fmaxf(fmaxf(lz - sz, sz - (lz + HCEL)), 0.f);
            if (ddx * ddx + ddy * ddy + ddz * ddz > R2) continue;
            int cell = (Z * GC + Y) * GC + X;
            int cn = min(cellcnt[cell], SLOTS);
            if (cn == 0) continue;
            int sl = atomicAdd(&ncl, 1);
            if (sl < 256) { ccell[sl] = cell; ccnt[sl] = cn; }
        }
    }
    __syncthreads();
    const int nclc = min(ncl, 256);

    // ---- prefix over cell counts (shuffle, 2 barriers) ----
    {
        int v = 0;
        if (t < 256) {
            if (t < nclc) v = ccnt[t];
#pragma unroll
            for (int off = 1; off < 64; off <<= 1) {
                int x = __shfl_up(v, off);
                if (lane >= off) v += x;
            }
            if (lane == 63) wsum[w] = v;
        }
        __syncthreads();
        if (t < 256) {
            int add = 0;
#pragma unroll
            for (int j = 0; j < 4; j++) if (j < w) add += wsum[j];
            cpre[t] = v + add;
        }
        __syncthreads();
    }
    const int tot = cpre[255];
    const int Mg  = min(tot, CAP);

    // ---- dense gather of ALL ball-cell points (no filter, no atomics) ----
    for (int j0 = 0; j0 < Mg; j0 += TPB) {
        int j = j0 + t;
        if (j < Mg) {
            int lo = 0;
#pragma unroll
            for (int st = 128; st; st >>= 1) {
                int nlo = lo + st;
                if (nlo <= 256 && cpre[nlo - 1] <= j) lo = nlo;
            }
            int off = j - (lo ? cpre[lo - 1] : 0);
            int u = ccell[lo] * SLOTS + off;
            float4 P = pos4s[u];
            float dx = sx - P.x, dy = sy - P.y, dz = sz - P.z;
            d2buf[j] = dx * dx + dy * dy + dz * dz;
            obuf[j]  = origidx[u];
            pxb[j] = P.x; pyb[j] = P.y; pzb[j] = P.z;
        }
    }
    // overflow spill list (expected empty), dense append after Mg
    const int no = min(min(cellcnt[4096], OCAP), CAP - Mg);
    if (t < no) {
        float4 P = ovfpos[t];
        float dx = sx - P.x, dy = sy - P.y, dz = sz - P.z;
        d2buf[Mg + t] = dx * dx + dy * dy + dz * dz;
        obuf[Mg + t]  = ovfidx[t];
        pxb[Mg + t] = P.x; pyb[Mg + t] = P.y; pzb[Mg + t] = P.z;
    }
    const int M = Mg + no;
    const int Mpad = (M + 3) & ~3;
    if (M + t < Mpad) { d2buf[M + t] = INFINITY; obuf[M + t] = 0x7fffffff; }
    __syncthreads();

    // ---- exact rank-merge -> top-32 (store winning SLOT) ----
    for (int u = t; u < M; u += TPB) {
        float myv = d2buf[u];
        int   myo = obuf[u];
        int rank = 0;
        for (int v2 = 0; v2 < Mpad; v2 += 4) {
            float4 dv = *(const float4*)&d2buf[v2];
            int4   iv = *(const int4*)&obuf[v2];
            rank += (dv.x < myv) || (dv.x == myv && iv.x < myo);
            rank += (dv.y < myv) || (dv.y == myv && iv.y < myo);
            rank += (dv.z < myv) || (dv.z == myv && iv.z < myo);
            rank += (dv.w < myv) || (dv.w == myv && iv.w < myo);
        }
        if (rank < KNB) selo[rank] = u;
    }
    __syncthreads();
    if (t < KNB) {
        int u = selo[t];
        float rx = sx - pxb[u], ry = sy - pyb[u], rz = sz - pzb[u];
        float dd = sqrtf(d2buf[u]);
        rf[t][0] = rx; rf[t][1] = ry; rf[t][2] = rz; rf[t][3] = dd;
    }
    __syncthreads();   // select stage dead; msg takes pool

    // ---- sincos embed -> msg[k][i] bf16, row-XOR swizzle ----
#pragma unroll
    for (int n = 0; n < 8; n++) {
        int item = t + n * TPB;
        int f = item & 31;
        int c = (item >> 5) & 3;
        int k = item >> 7;
        float ang = rf[k][c] * exp2f(-(float)f * (L2_10000 / 32.f));
        int swz = (k & 7) << 3;
        msg[((k << 8) | (c * 64 + f))      ^ swz] = f2bf(__sinf(ang));
        msg[((k << 8) | (c * 64 + 32 + f)) ^ swz] = f2bf(__cosf(ang));
    }
    __syncthreads();

    // ---- MFMA GEMM1: wave w owns j-rows [32w, 32w+32); epilogue -> hbB bf16 ----
    {
        const int lr = lane & 15;
        const int lg = lane >> 4;
        f32x4 acc00 = {0,0,0,0}, acc01 = {0,0,0,0};
        f32x4 acc10 = {0,0,0,0}, acc11 = {0,0,0,0};
#pragma unroll
        for (int kk = 0; kk < 8; kk++) {
            const int i0 = kk * 32 + lg * 8;
            bf16x8 a0 = *(const bf16x8*)(W1t + ((32 * w      + lr) << 8) + i0);
            bf16x8 a1 = *(const bf16x8*)(W1t + ((32 * w + 16 + lr) << 8) + i0);
            const int swz = (lr & 7) << 3;
            bf16x8 b0  = *(const bf16x8*)(msg + ((( lr       << 8) | i0) ^ swz));
            bf16x8 b1v = *(const bf16x8*)(msg + ((((lr + 16) << 8) | i0) ^ swz));
            acc00 = __builtin_amdgcn_mfma_f32_16x16x32_bf16(a0, b0,  acc00, 0, 0, 0);
            acc01 = __builtin_amdgcn_mfma_f32_16x16x32_bf16(a0, b1v, acc01, 0, 0, 0);
            acc10 = __builtin_amdgcn_mfma_f32_16x16x32_bf16(a1, b0,  acc10, 0, 0, 0);
            acc11 = __builtin_amdgcn_mfma_f32_16x16x32_bf16(a1, b1v, acc11, 0, 0, 0);
        }
        float part[8];
#pragma unroll
        for (int mm = 0; mm < 2; mm++)
#pragma unroll
            for (int r = 0; r < 4; r++) {
                int j = 32 * w + 16 * mm + 4 * lg + r;
                float bj = b1[j];
                float h0 = (mm == 0 ? acc00[r] : acc10[r]) + bj;
                float h1 = (mm == 0 ? acc01[r] : acc11[r]) + bj;
                part[mm * 4 + r] = gelu_fast(h0) + gelu_fast(h1);
            }
#pragma unroll
        for (int off = 1; off < 16; off <<= 1)
#pragma unroll
            for (int u = 0; u < 8; u++)
                part[u] += __shfl_xor(part[u], off);
        if (lr == 0) {
#pragma unroll
            for (int u = 0; u < 8; u++) {
                int mm = u >> 2, r = u & 3;
                hbB[s * H + 32 * w + 16 * mm + 4 * lg + r] = f2bf(part[u] * (1.0f / 32.0f));
            }
        }
    }
}

// ---- mfma_out2: 64 blocks x 512; 16 s-rows each.
//  stage1: agg[j][s] = sum_i W2t[j][i]*hbB[s][i] + b2  -> swizzled LDS bf16
//  stage2: out[s][jo] = sum_io Wpt[jo][io]*feats[s][io] + bp ----
__global__ __launch_bounds__(512)
void mfma_out2(const ushort* __restrict__ hbB, const ushort* __restrict__ supEB,
               const ushort* __restrict__ W2t, const float* __restrict__ b2,
               const ushort* __restrict__ Wpt, const float* __restrict__ bp,
               float* __restrict__ out)
{
    __shared__ ushort agg[16 * 256];   // [s_local][j], row-XOR swizzled
    const int bm   = blockIdx.x;
    const int t    = threadIdx.x;
    const int lane = t & 63;
    const int w    = t >> 6;
    const int lr   = lane & 15;
    const int lg   = lane >> 4;

    // stage 1
    f32x4 acc1[2] = {{0,0,0,0},{0,0,0,0}};
#pragma unroll
    for (int kk = 0; kk < 8; kk++) {
        const int i0 = kk * 32 + lg * 8;
        bf16x8 bf = *(const bf16x8*)(hbB + (16 * bm + lr) * H + i0);
        bf16x8 a0 = *(const bf16x8*)(W2t + ((32 * w      + lr) << 8) + i0);
        bf16x8 a1 = *(const bf16x8*)(W2t + ((32 * w + 16 + lr) << 8) + i0);
        acc1[0] = __builtin_amdgcn_mfma_f32_16x16x32_bf16(a0, bf, acc1[0], 0, 0, 0);
        acc1[1] = __builtin_amdgcn_mfma_f32_16x16x32_bf16(a1, bf, acc1[1], 0, 0, 0);
    }
#pragma unroll
    for (int mt = 0; mt < 2; mt++)
#pragma unroll
        for (int r = 0; r < 4; r++) {
            int j = 32 * w + 16 * mt + 4 * lg + r;
            int sl = lane & 15;
            float v = acc1[mt][r] + b2[j];
            agg[((sl << 8) | j) ^ ((sl & 7) << 3)] = f2bf(v);
        }
    __syncthreads();

    // stage 2
    f32x4 acc2[2] = {{0,0,0,0},{0,0,0,0}};
#pragma unroll
    for (int kk = 0; kk < 16; kk++) {
        const int io = kk * 32 + lg * 8;
        bf16x8 bf;
        if (kk < 8) {
            bf = *(const bf16x8*)(supEB + (16 * bm + lr) * H + io);
        } else {
            int c = io - 256;
            bf = *(const bf16x8*)(agg + (((lr << 8) | c) ^ ((lr & 7) << 3)));
        }
        bf16x8 a0 = *(const bf16x8*)(Wpt + (32 * w      + lr) * 512 + io);
        bf16x8 a1 = *(const bf16x8*)(Wpt + (32 * w + 16 + lr) * 512 + io);
        acc2[0] = __builtin_amdgcn_mfma_f32_16x16x32_bf16(a0, bf, acc2[0], 0, 0, 0);
        acc2[1] = __builtin_amdgcn_mfma_f32_16x16x32_bf16(a1, bf, acc2[1], 0, 0, 0);
    }
#pragma unroll
    for (int mt = 0; mt < 2; mt++)
#pragma unroll
        for (int r = 0; r < 4; r++) {
            int jo = 32 * w + 16 * mt + 4 * lg + r;
            int srow = 16 * bm + (lane & 15);
            out[srow * H + jo] = acc2[mt][r] + bp[jo];
        }
}

extern "C" void kernel_launch(void* const* d_in, const int* in_sizes, int n_in,
                              void* d_out, int out_size, void* d_ws, size_t ws_size,
                              hipStream_t stream) {
    const float* pos = (const float*)d_in[0];
    const int*   sup = (const int*)d_in[1];
    const float* W1  = (const float*)d_in[2];
    const float* b1  = (const float*)d_in[3];
    const float* W2  = (const float*)d_in[4];
    const float* b2  = (const float*)d_in[5];
    const float* Wp  = (const float*)d_in[6];
    const float* bp  = (const float*)d_in[7];

    const int N = in_sizes[0] / 3;
    const int S = in_sizes[1];
    float* out = (float*)d_out;

    char* ws = (char*)d_ws;
    ushort* W1t     = (ushort*)ws;                      // 128 KB
    ushort* Wpt     = (ushort*)(ws + (128 << 10));      // 256 KB bf16 [256][512]
    ushort* W2t     = (ushort*)(ws + (384 << 10));      // 128 KB bf16 [256][256]
    float4* pos4s   = (float4*)(ws + (512 << 10));      // 2 MB
    int*    origidx = (int*)(ws + (2560 << 10));        // 512 KB
    int*    cellcnt = (int*)(ws + (3072 << 10));        // 4097 ints
    int*    ovfidx  = (int*)(ws + (3092 << 10));        // 1 KB
    float4* ovfpos  = (float4*)(ws + (3096 << 10));     // 4 KB
    ushort* supEB   = (ushort*)(ws + (3104 << 10));     // 512 KB bf16 [S][256]
    ushort* hbB     = (ushort*)(ws + (3616 << 10));     // 512 KB bf16 [S][256]

    hipMemsetAsync(cellcnt, 0, 4097 * sizeof(int), stream);
    const int nscat = (N + 1023) / 1024;
    prep<<<256 + nscat, 256, 0, stream>>>(W1, Wp, W2, pos, N,
                                          W1t, Wpt, W2t, pos4s,
                                          origidx, cellcnt, ovfidx, ovfpos);
    fused_knn_mlp<<<S, TPB, 0, stream>>>(pos, pos4s, origidx, cellcnt,
                                         ovfidx, ovfpos, sup,
                                         W1t, b1, supEB, hbB);
    mfma_out2<<<S / 16, 512, 0, stream>>>(hbB, supEB, W2t, b2, Wpt, bp, out);
}

// Round 19
// 92.477 us; speedup vs baseline: 1.7913x; 1.7913x over previous
//
#include <hip/hip_runtime.h>
#include <hip/hip_bf16.h>
#include <math.h>

typedef short bf16x8 __attribute__((ext_vector_type(8)));
typedef float f32x4  __attribute__((ext_vector_type(4)));

constexpr int   H     = 256;
constexpr int   KNB   = 32;
constexpr int   TPB   = 512;     // 8 waves/block
constexpr int   GC    = 16;      // bin-grid cells per dim
constexpr float HINV  = 1.6f;    // GC / 10.0
constexpr float HCEL  = 0.625f;  // 10.0 / GC
constexpr int   SLOTS = 32;      // slots per cell (avg fill ~12.2; overflow spills)
constexpr int   OCAP  = 256;     // overflow list capacity
constexpr int   CAP   = 512;     // candidate buffer (M1 ~40 + tot2 ~150)

__device__ __forceinline__ ushort f2bf(float x) {
    unsigned u = __float_as_uint(x);
    u += 0x7FFF + ((u >> 16) & 1);
    return (ushort)(u >> 16);
}

__device__ __forceinline__ float gelu_fast(float x) {
    float u = 0.7978845608028654f * (x + 0.044715f * x * x * x);
    float t = exp2f(-2.885390081777927f * u);
    return x / (1.0f + t);
}

__device__ __forceinline__ int cell_of(float x, float y, float z) {
    int cx = min(GC - 1, max(0, (int)(x * HINV)));
    int cy = min(GC - 1, max(0, (int)(y * HINV)));
    int cz = min(GC - 1, max(0, (int)(z * HINV)));
    return (cz * GC + cy) * GC + cx;
}

// ---- prep: W1t (b<64), Wpt (64..191), W2t (192..255), vector scatter (256..) ----
__global__ __launch_bounds__(256)
void prep(const float* __restrict__ W1, const float* __restrict__ Wp,
          const float* __restrict__ W2, const float* __restrict__ pos, int N,
          ushort* __restrict__ W1t, ushort* __restrict__ Wpt,
          ushort* __restrict__ W2t, float4* __restrict__ pos4s,
          int* __restrict__ origidx, int* __restrict__ cellcnt,
          int* __restrict__ ovfidx, float4* __restrict__ ovfpos) {
    const int b = blockIdx.x;
    if (b < 64) {
        __shared__ float tile[32][33];
        const int ti = b >> 3, tj = b & 7;
        const int r  = threadIdx.x >> 5, c = threadIdx.x & 31;
#pragma unroll
        for (int rr = r; rr < 32; rr += 8)
            tile[rr][c] = W1[(ti * 32 + rr) * H + tj * 32 + c];
        __syncthreads();
#pragma unroll
        for (int rr = r; rr < 32; rr += 8)
            W1t[(tj * 32 + rr) * H + ti * 32 + c] = f2bf(tile[c][rr]);
    } else if (b < 192) {
        __shared__ float tile[32][33];
        const int b2 = b - 64;
        const int ti = b2 >> 3, tj = b2 & 7;
        const int r  = threadIdx.x >> 5, c = threadIdx.x & 31;
#pragma unroll
        for (int rr = r; rr < 32; rr += 8)
            tile[rr][c] = Wp[(ti * 32 + rr) * H + tj * 32 + c];
        __syncthreads();
#pragma unroll
        for (int rr = r; rr < 32; rr += 8)
            Wpt[(tj * 32 + rr) * (2 * H) + ti * 32 + c] = f2bf(tile[c][rr]);
    } else if (b < 256) {
        __shared__ float tile[32][33];
        const int b2 = b - 192;
        const int ti = b2 >> 3, tj = b2 & 7;
        const int r  = threadIdx.x >> 5, c = threadIdx.x & 31;
#pragma unroll
        for (int rr = r; rr < 32; rr += 8)
            tile[rr][c] = W2[(ti * 32 + rr) * H + tj * 32 + c];
        __syncthreads();
#pragma unroll
        for (int rr = r; rr < 32; rr += 8)
            W2t[(tj * 32 + rr) * H + ti * 32 + c] = f2bf(tile[c][rr]);
    } else {
        const int sb = b - 256;
        const int base = sb * 1024;
        const int t = threadIdx.x;
        auto scat = [&](float x, float y, float z, int i) {
            float4 P = make_float4(x, y, z, 0.f);
            int c = cell_of(x, y, z);
            int slot = atomicAdd(&cellcnt[c], 1);
            if (slot < SLOTS) {
                pos4s[c * SLOTS + slot] = P;
                origidx[c * SLOTS + slot] = i;
            } else {
                int o = atomicAdd(&cellcnt[4096], 1);
                if (o < OCAP) { ovfpos[o] = P; ovfidx[o] = i; }
            }
        };
        if (base + 1024 <= N) {
            const float4* p4 = (const float4*)(pos + (size_t)base * 3);
            float4 f0 = p4[3 * t + 0];
            float4 f1 = p4[3 * t + 1];
            float4 f2 = p4[3 * t + 2];
            const int ib = base + 4 * t;
            scat(f0.x, f0.y, f0.z, ib + 0);
            scat(f0.w, f1.x, f1.y, ib + 1);
            scat(f1.z, f1.w, f2.x, ib + 2);
            scat(f2.y, f2.z, f2.w, ib + 3);
        } else {
            for (int i = base + t; i < N; i += 256)
                scat(pos[3 * i], pos[3 * i + 1], pos[3 * i + 2], i);
        }
    }
}

// ---- fused: select (cell-tau -> phase1 tau* -> phase2 dense -> top-32) ->
//      embed -> MFMA GEMM1 -> gelu/mean -> hbB (bf16); supE -> supEB ----
__global__ __launch_bounds__(TPB, 8)
void fused_knn_mlp(const float* __restrict__ pos,
                   const float4* __restrict__ pos4s,
                   const int* __restrict__ origidx,
                   const int* __restrict__ cellcnt,
                   const int* __restrict__ ovfidx, const float4* __restrict__ ovfpos,
                   const int* __restrict__ supidx,
                   const ushort* __restrict__ W1t, const float* __restrict__ b1,
                   ushort* __restrict__ supEB, ushort* __restrict__ hbB)
{
    __shared__ __align__(16) char pool[16384];
    float* amaxd = (float*)pool;
    int*   acnt  = (int*)(pool + 512);
    int*   ccell = (int*)(pool + 1024);
    int*   ccnt  = (int*)(pool + 2048);
    float* cmnd  = (float*)(pool + 3072);
    int*   cpre  = (int*)(pool + 4096);
    float* d2buf = (float*)(pool + 5120);
    int*   obuf  = (int*)(pool + 7168);
    float* pxb   = (float*)(pool + 9216);
    float* pyb   = (float*)(pool + 11264);
    float* pzb   = (float*)(pool + 13312);
    ushort* msg  = (ushort*)pool;

    __shared__ float rf[KNB][5];
    __shared__ int   selo[KNB];
    __shared__ int   wsum[4];
    __shared__ float tau2_sh, tau32_sh;
    __shared__ int   ncl;

    const int s    = blockIdx.x;
    const int t    = threadIdx.x;
    const int lane = t & 63;
    const int w    = t >> 6;       // wave 0..7

    const int sidx = supidx[s];
    const float sx = pos[3 * sidx], sy = pos[3 * sidx + 1], sz = pos[3 * sidx + 2];

    constexpr float L2_10000 = 13.287712379549449f;

    if (t == 0) { ncl = 0; tau2_sh = 301.f; }

    // ---- stage A: issue cellcnt window loads FIRST (latency hidden by supE) ----
    const int scx = min(GC - 1, max(0, (int)(sx * HINV)));
    const int scy = min(GC - 1, max(0, (int)(sy * HINV)));
    const int scz = min(GC - 1, max(0, (int)(sz * HINV)));
    const int ax0 = max(0, scx - 2), ax1 = min(GC - 1, scx + 2);
    const int ay0 = max(0, scy - 2), ay1 = min(GC - 1, scy + 2);
    const int az0 = max(0, scz - 2), az1 = min(GC - 1, scz + 2);
    const int anx = ax1 - ax0 + 1, any_ = ay1 - ay0 + 1, anz = az1 - az0 + 1;
    const int an  = anx * any_ * anz;    // <= 125
    if (t < an) {
        int ci = t;
        int X = ax0 + ci % anx, rem = ci / anx;
        int Y = ay0 + rem % any_, Z = az0 + rem / any_;
        int cell = (Z * GC + Y) * GC + X;
        acnt[ci] = min(cellcnt[cell], SLOTS);
        float lx = X * HCEL, ly = Y * HCEL, lz = Z * HCEL;
        float mx = fmaxf(fabsf(sx - lx), fabsf(lx + HCEL - sx));
        float my = fmaxf(fabsf(sy - ly), fabsf(ly + HCEL - sy));
        float mz = fmaxf(fabsf(sz - lz), fabsf(lz + HCEL - sz));
        amaxd[ci] = mx * mx + my * my + mz * mz;
    }

    // supE embed -> supEB[s][0..255] (bf16), overlapping the loads above
    if (t < 256) {
        float se = 0.f;
        if (t < 252) {
            int c  = t / 84;
            int rr = t - c * 84;
            int f  = (rr < 42) ? rr : rr - 42;
            float coord = (c == 0) ? sx : ((c == 1) ? sy : sz);
            float ang = coord * exp2f(-(float)f * (L2_10000 / 42.f));
            se = (rr < 42) ? __sinf(ang) : __cosf(ang);
        }
        supEB[s * H + t] = f2bf(se);
    }
    __syncthreads();
    if (t < an) {
        int ci = t;
        float myv = amaxd[ci];
        int Sc = 0;
        for (int j = 0; j < an; j++) {
            bool less = (amaxd[j] < myv) || (amaxd[j] == myv && j < ci);
            Sc += less ? acnt[j] : 0;
        }
        if (Sc < KNB && KNB <= Sc + acnt[ci]) tau2_sh = myv;
    }
    __syncthreads();
    const float tau2 = tau2_sh;
    const float R2 = tau2 + 1e-3f;
    const float R  = sqrtf(R2);
    if (t == 0) tau32_sh = R2;   // fallback if phase1 < 32

    // ---- stage B: build ball-cell list (cell, cnt|p1flag, mind2) ----
    const int bx0 = max(0, (int)floorf((sx - R) * HINV));
    const int bx1 = min(GC - 1, (int)floorf((sx + R) * HINV));
    const int by0 = max(0, (int)floorf((sy - R) * HINV));
    const int by1 = min(GC - 1, (int)floorf((sy + R) * HINV));
    const int bz0 = max(0, (int)floorf((sz - R) * HINV));
    const int bz1 = min(GC - 1, (int)floorf((sz + R) * HINV));
    const bool inwin = (bx0 >= ax0 && bx1 <= ax1 && by0 >= ay0 && by1 <= ay1 &&
                        bz0 >= az0 && bz1 <= az1);
    if (inwin) {
        if (t < an) {
            int ci = t;
            int cn = acnt[ci];
            if (cn > 0) {
                int X = ax0 + ci % anx, rem = ci / anx;
                int Y = ay0 + rem % any_, Z = az0 + rem / any_;
                float lx = X * HCEL, ly = Y * HCEL, lz = Z * HCEL;
                float ddx = fmaxf(fmaxf(lx - sx, sx - (lx + HCEL)), 0.f);
                float ddy = fmaxf(fmaxf(ly - sy, sy - (ly + HCEL)), 0.f);
                float ddz = fmaxf(fmaxf(lz - sz, sz - (lz + HCEL)), 0.f);
                float mnd = ddx * ddx + ddy * ddy + ddz * ddz;
                if (mnd <= R2) {
                    int p1 = (amaxd[ci] <= tau2) ? 1 : 0;
                    int cell = (Z * GC + Y) * GC + X;
                    int sl = atomicAdd(&ncl, 1);
                    if (sl < 256) { ccell[sl] = cell; ccnt[sl] = cn | (p1 << 8); cmnd[sl] = mnd; }
                }
            }
        }
    } else {
        const int nbx = bx1 - bx0 + 1, nby = by1 - by0 + 1, nbz = bz1 - bz0 + 1;
        const int ncb = nbx * nby * nbz;
        for (int ci = t; ci < ncb; ci += TPB) {
            int X = bx0 + ci % nbx, rem = ci / nbx;
            int Y = by0 + rem % nby, Z = bz0 + rem / nby;
            float lx = X * HCEL, ly = Y * HCEL, lz = Z * HCEL;
            float ddx = fmaxf(fmaxf(lx - sx, sx - (lx + HCEL)), 0.f);
            float ddy = fmaxf(fmaxf(ly - sy, sy - (ly + HCEL)), 0.f);
            float ddz = fmaxf(fmaxf(lz - sz, sz - (lz + HCEL)), 0.f);
            float mnd = ddx * ddx + ddy * ddy + ddz * ddz;
            if (mnd > R2) continue;
            int cell = (Z * GC + Y) * GC + X;
            int cn = min(cellcnt[cell], SLOTS);
            if (cn == 0) continue;
            float mx = fmaxf(fabsf(sx - lx), fabsf(lx + HCEL - sx));
            float my = fmaxf(fabsf(sy - ly), fabsf(ly + HCEL - sy));
            float mz = fmaxf(fabsf(sz - lz), fabsf(lz + HCEL - sz));
            float amx = mx * mx + my * my + mz * mz;
            int p1 = (amx <= tau2) ? 1 : 0;
            int sl = atomicAdd(&ncl, 1);
            if (sl < 256) { ccell[sl] = cell; ccnt[sl] = cn | (p1 << 8); cmnd[sl] = mnd; }
        }
    }
    __syncthreads();
    const int nclc = min(ncl, 256);

    auto build_prefix = [&](int phase, float tlim) -> int {
        int v = 0;
        if (t < 256) {
            if (t < nclc) {
                int cc = ccnt[t];
                int cn = cc & 0xff;
                int p1 = cc >> 8;
                v = (phase == 1) ? (p1 ? cn : 0)
                                 : ((!p1 && cmnd[t] <= tlim) ? cn : 0);
            }
#pragma unroll
            for (int off = 1; off < 64; off <<= 1) {
                int x = __shfl_up(v, off);
                if (lane >= off) v += x;
            }
            if (lane == 63) wsum[w] = v;
        }
        __syncthreads();
        if (t < 256) {
            int add = 0;
#pragma unroll
            for (int j = 0; j < 4; j++) if (j < w) add += wsum[j];
            cpre[t] = v + add;
        }
        __syncthreads();
        return cpre[255];
    };
    auto bsearch = [&](int j) -> int {
        int lo = 0;
#pragma unroll
        for (int st = 128; st; st >>= 1) {
            int nlo = lo + st;
            if (nlo <= 256 && cpre[nlo - 1] <= j) lo = nlo;
        }
        return lo;
    };

    // ---- phase 1: gather ALL points of P1 cells (dense, no atomics) ----
    const int tot1 = build_prefix(1, 0.f);
    const int M1 = min(tot1, CAP);
    if (t < M1) {
        int j = t;
        int lo = bsearch(j);
        int off = j - (lo ? cpre[lo - 1] : 0);
        int u = ccell[lo] * SLOTS + off;
        float4 P = pos4s[u];
        float dx = sx - P.x, dy = sy - P.y, dz = sz - P.z;
        d2buf[j] = dx * dx + dy * dy + dz * dz;
        obuf[j]  = origidx[u];
        pxb[j] = P.x; pyb[j] = P.y; pzb[j] = P.z;
    }
    const int Mp1 = (M1 + 3) & ~3;
    if (M1 + t < Mp1) { d2buf[M1 + t] = INFINITY; obuf[M1 + t] = 0x7fffffff; }
    __syncthreads();

    // exact 32nd-smallest of phase-1 set -> tau* (<= tau2 by construction)
    if (t < M1) {
        int u = t;
        float myv = d2buf[u];
        int   myo = obuf[u];
        int rank = 0;
        for (int v2 = 0; v2 < Mp1; v2 += 4) {
            float4 dv = *(const float4*)&d2buf[v2];
            int4   iv = *(const int4*)&obuf[v2];
            rank += (dv.x < myv) || (dv.x == myv && iv.x < myo);
            rank += (dv.y < myv) || (dv.y == myv && iv.y < myo);
            rank += (dv.z < myv) || (dv.z == myv && iv.z < myo);
            rank += (dv.w < myv) || (dv.w == myv && iv.w < myo);
        }
        if (rank == KNB - 1) tau32_sh = myv;
    }
    __syncthreads();
    const float tau32 = tau32_sh;

    // ---- phase 2: cells with mind2 <= tau*, DENSE append (rank filters extras) ----
    const int tot2 = build_prefix(2, tau32);
    const int M2 = min(tot2, CAP - M1);
    for (int j0 = 0; j0 < M2; j0 += TPB) {
        int j = j0 + t;
        if (j < M2) {
            int lo = bsearch(j);
            int off = j - (lo ? cpre[lo - 1] : 0);
            int u = ccell[lo] * SLOTS + off;
            float4 P = pos4s[u];
            float dx = sx - P.x, dy = sy - P.y, dz = sz - P.z;
            d2buf[M1 + j] = dx * dx + dy * dy + dz * dz;
            obuf[M1 + j]  = origidx[u];
            pxb[M1 + j] = P.x; pyb[M1 + j] = P.y; pzb[M1 + j] = P.z;
        }
    }
    // overflow spill list (expected empty), dense append
    const int no = min(min(cellcnt[4096], OCAP), CAP - M1 - M2);
    if (t < no) {
        float4 P = ovfpos[t];
        float dx = sx - P.x, dy = sy - P.y, dz = sz - P.z;
        d2buf[M1 + M2 + t] = dx * dx + dy * dy + dz * dz;
        obuf[M1 + M2 + t]  = ovfidx[t];
        pxb[M1 + M2 + t] = P.x; pyb[M1 + M2 + t] = P.y; pzb[M1 + M2 + t] = P.z;
    }
    const int M = M1 + M2 + no;
    const int Mpad = (M + 3) & ~3;
    if (M + t < Mpad) { d2buf[M + t] = INFINITY; obuf[M + t] = 0x7fffffff; }
    __syncthreads();

    // ---- final exact rank-merge -> top-32 (store winning SLOT) ----
    if (t < M) {
        int u = t;
        float myv = d2buf[u];
        int   myo = obuf[u];
        int rank = 0;
        for (int v2 = 0; v2 < Mpad; v2 += 4) {
            float4 dv = *(const float4*)&d2buf[v2];
            int4   iv = *(const int4*)&obuf[v2];
            rank += (dv.x < myv) || (dv.x == myv && iv.x < myo);
            rank += (dv.y < myv) || (dv.y == myv && iv.y < myo);
            rank += (dv.z < myv) || (dv.z == myv && iv.z < myo);
            rank += (dv.w < myv) || (dv.w == myv && iv.w < myo);
        }
        if (rank < KNB) selo[rank] = u;
    }
    __syncthreads();
    if (t < KNB) {
        int u = selo[t];
        float rx = sx - pxb[u], ry = sy - pyb[u], rz = sz - pzb[u];
        float dd = sqrtf(d2buf[u]);
        rf[t][0] = rx; rf[t][1] = ry; rf[t][2] = rz; rf[t][3] = dd;
    }
    __syncthreads();   // select stage dead; msg takes pool

    // ---- sincos embed -> msg[k][i] bf16, row-XOR swizzle ----
#pragma unroll
    for (int n = 0; n < 8; n++) {
        int item = t + n * TPB;
        int f = item & 31;
        int c = (item >> 5) & 3;
        int k = item >> 7;
        float ang = rf[k][c] * exp2f(-(float)f * (L2_10000 / 32.f));
        int swz = (k & 7) << 3;
        msg[((k << 8) | (c * 64 + f))      ^ swz] = f2bf(__sinf(ang));
        msg[((k << 8) | (c * 64 + 32 + f)) ^ swz] = f2bf(__cosf(ang));
    }
    __syncthreads();

    // ---- MFMA GEMM1: wave w owns j-rows [32w, 32w+32); epilogue -> hbB bf16 ----
    {
        const int lr = lane & 15;
        const int lg = lane >> 4;
        f32x4 acc00 = {0,0,0,0}, acc01 = {0,0,0,0};
        f32x4 acc10 = {0,0,0,0}, acc11 = {0,0,0,0};
#pragma unroll
        for (int kk = 0; kk < 8; kk++) {
            const int i0 = kk * 32 + lg * 8;
            bf16x8 a0 = *(const bf16x8*)(W1t + ((32 * w      + lr) << 8) + i0);
            bf16x8 a1 = *(const bf16x8*)(W1t + ((32 * w + 16 + lr) << 8) + i0);
            const int swz = (lr & 7) << 3;
            bf16x8 b0  = *(const bf16x8*)(msg + ((( lr       << 8) | i0) ^ swz));
            bf16x8 b1v = *(const bf16x8*)(msg + ((((lr + 16) << 8) | i0) ^ swz));
            acc00 = __builtin_amdgcn_mfma_f32_16x16x32_bf16(a0, b0,  acc00, 0, 0, 0);
            acc01 = __builtin_amdgcn_mfma_f32_16x16x32_bf16(a0, b1v, acc01, 0, 0, 0);
            acc10 = __builtin_amdgcn_mfma_f32_16x16x32_bf16(a1, b0,  acc10, 0, 0, 0);
            acc11 = __builtin_amdgcn_mfma_f32_16x16x32_bf16(a1, b1v, acc11, 0, 0, 0);
        }
        float part[8];
#pragma unroll
        for (int mm = 0; mm < 2; mm++)
#pragma unroll
            for (int r = 0; r < 4; r++) {
                int j = 32 * w + 16 * mm + 4 * lg + r;
                float bj = b1[j];
                float h0 = (mm == 0 ? acc00[r] : acc10[r]) + bj;
                float h1 = (mm == 0 ? acc01[r] : acc11[r]) + bj;
                part[mm * 4 + r] = gelu_fast(h0) + gelu_fast(h1);
            }
#pragma unroll
        for (int off = 1; off < 16; off <<= 1)
#pragma unroll
            for (int u = 0; u < 8; u++)
                part[u] += __shfl_xor(part[u], off);
        if (lr == 0) {
#pragma unroll
            for (int u = 0; u < 8; u++) {
                int mm = u >> 2, r = u & 3;
                hbB[s * H + 32 * w + 16 * mm + 4 * lg + r] = f2bf(part[u] * (1.0f / 32.0f));
            }
        }
    }
}

// ---- mfma_out2: 64 blocks x 512; 16 s-rows each.
//  stage1: agg[j][s] = sum_i W2t[j][i]*hbB[s][i] + b2  -> swizzled LDS bf16
//  stage2: out[s][jo] = sum_io Wpt[jo][io]*feats[s][io] + bp ----
__global__ __launch_bounds__(512)
void mfma_out2(const ushort* __restrict__ hbB, const ushort* __restrict__ supEB,
               const ushort* __restrict__ W2t, const float* __restrict__ b2,
               const ushort* __restrict__ Wpt, const float* __restrict__ bp,
               float* __restrict__ out)
{
    __shared__ ushort agg[16 * 256];   // [s_local][j], row-XOR swizzled
    const int bm   = blockIdx.x;
    const int t    = threadIdx.x;
    const int lane = t & 63;
    const int w    = t >> 6;
    const int lr   = lane & 15;
    const int lg   = lane >> 4;

    // stage 1
    f32x4 acc1[2] = {{0,0,0,0},{0,0,0,0}};
#pragma unroll
    for (int kk = 0; kk < 8; kk++) {
        const int i0 = kk * 32 + lg * 8;
        bf16x8 bf = *(const bf16x8*)(hbB + (16 * bm + lr) * H + i0);
        bf16x8 a0 = *(const bf16x8*)(W2t + ((32 * w      + lr) << 8) + i0);
        bf16x8 a1 = *(const bf16x8*)(W2t + ((32 * w + 16 + lr) << 8) + i0);
        acc1[0] = __builtin_amdgcn_mfma_f32_16x16x32_bf16(a0, bf, acc1[0], 0, 0, 0);
        acc1[1] = __builtin_amdgcn_mfma_f32_16x16x32_bf16(a1, bf, acc1[1], 0, 0, 0);
    }
#pragma unroll
    for (int mt = 0; mt < 2; mt++)
#pragma unroll
        for (int r = 0; r < 4; r++) {
            int j = 32 * w + 16 * mt + 4 * lg + r;
            int sl = lane & 15;
            float v = acc1[mt][r] + b2[j];
            agg[((sl << 8) | j) ^ ((sl & 7) << 3)] = f2bf(v);
        }
    __syncthreads();

    // stage 2
    f32x4 acc2[2] = {{0,0,0,0},{0,0,0,0}};
#pragma unroll
    for (int kk = 0; kk < 16; kk++) {
        const int io = kk * 32 + lg * 8;
        bf16x8 bf;
        if (kk < 8) {
            bf = *(const bf16x8*)(supEB + (16 * bm + lr) * H + io);
        } else {
            int c = io - 256;
            bf = *(const bf16x8*)(agg + (((lr << 8) | c) ^ ((lr & 7) << 3)));
        }
        bf16x8 a0 = *(const bf16x8*)(Wpt + (32 * w      + lr) * 512 + io);
        bf16x8 a1 = *(const bf16x8*)(Wpt + (32 * w + 16 + lr) * 512 + io);
        acc2[0] = __builtin_amdgcn_mfma_f32_16x16x32_bf16(a0, bf, acc2[0], 0, 0, 0);
        acc2[1] = __builtin_amdgcn_mfma_f32_16x16x32_bf16(a1, bf, acc2[1], 0, 0, 0);
    }
#pragma unroll
    for (int mt = 0; mt < 2; mt++)
#pragma unroll
        for (int r = 0; r < 4; r++) {
            int jo = 32 * w + 16 * mt + 4 * lg + r;
            int srow = 16 * bm + (lane & 15);
            out[srow * H + jo] = acc2[mt][r] + bp[jo];
        }
}

extern "C" void kernel_launch(void* const* d_in, const int* in_sizes, int n_in,
                              void* d_out, int out_size, void* d_ws, size_t ws_size,
                              hipStream_t stream) {
    const float* pos = (const float*)d_in[0];
    const int*   sup = (const int*)d_in[1];
    const float* W1  = (const float*)d_in[2];
    const float* b1  = (const float*)d_in[3];
    const float* W2  = (const float*)d_in[4];
    const float* b2  = (const float*)d_in[5];
    const float* Wp  = (const float*)d_in[6];
    const float* bp  = (const float*)d_in[7];

    const int N = in_sizes[0] / 3;
    const int S = in_sizes[1];
    float* out = (float*)d_out;

    char* ws = (char*)d_ws;
    ushort* W1t     = (ushort*)ws;                      // 128 KB
    ushort* Wpt     = (ushort*)(ws + (128 << 10));      // 256 KB bf16 [256][512]
    ushort* W2t     = (ushort*)(ws + (384 << 10));      // 128 KB bf16 [256][256]
    float4* pos4s   = (float4*)(ws + (512 << 10));      // 2 MB
    int*    origidx = (int*)(ws + (2560 << 10));        // 512 KB
    int*    cellcnt = (int*)(ws + (3072 << 10));        // 4097 ints
    int*    ovfidx  = (int*)(ws + (3092 << 10));        // 1 KB
    float4* ovfpos  = (float4*)(ws + (3096 << 10));     // 4 KB
    ushort* supEB   = (ushort*)(ws + (3104 << 10));     // 512 KB bf16 [S][256]
    ushort* hbB     = (ushort*)(ws + (3616 << 10));     // 512 KB bf16 [S][256]

    hipMemsetAsync(cellcnt, 0, 4097 * sizeof(int), stream);
    const int nscat = (N + 1023) / 1024;
    prep<<<256 + nscat, 256, 0, stream>>>(W1, Wp, W2, pos, N,
                                          W1t, Wpt, W2t, pos4s,
                                          origidx, cellcnt, ovfidx, ovfpos);
    fused_knn_mlp<<<S, TPB, 0, stream>>>(pos, pos4s, origidx, cellcnt,
                                         ovfidx, ovfpos, sup,
                                         W1t, b1, supEB, hbB);
    mfma_out2<<<S / 16, 512, 0, stream>>>(hbB, supEB, W2t, b2, Wpt, bp, out);
}

// Round 20
// 76.677 us; speedup vs baseline: 2.1604x; 1.2060x over previous
//
#include <hip/hip_runtime.h>
#include <hip/hip_bf16.h>
#include <math.h>

typedef short bf16x8 __attribute__((ext_vector_type(8)));
typedef float f32x4  __attribute__((ext_vector_type(4)));

constexpr int   H     = 256;
constexpr int   KNB   = 32;
constexpr int   TPB   = 512;     // 8 waves/block
constexpr int   GC    = 16;      // bin-grid cells per dim
constexpr float HINV  = 1.6f;    // GC / 10.0
constexpr float HCEL  = 0.625f;  // 10.0 / GC
constexpr int   SLOTS = 32;      // slots per cell (avg fill ~12.2; overflow spills)
constexpr int   OCAP  = 256;     // overflow list capacity
constexpr int   CAP   = 512;     // candidate buffer

__device__ __forceinline__ ushort f2bf(float x) {
    unsigned u = __float_as_uint(x);
    u += 0x7FFF + ((u >> 16) & 1);
    return (ushort)(u >> 16);
}

__device__ __forceinline__ float gelu_fast(float x) {
    float u = 0.7978845608028654f * (x + 0.044715f * x * x * x);
    float t = exp2f(-2.885390081777927f * u);
    return x / (1.0f + t);
}

__device__ __forceinline__ int cell_of(float x, float y, float z) {
    int cx = min(GC - 1, max(0, (int)(x * HINV)));
    int cy = min(GC - 1, max(0, (int)(y * HINV)));
    int cz = min(GC - 1, max(0, (int)(z * HINV)));
    return (cz * GC + cy) * GC + cx;
}

// ---- prep: W1t (b<64), Wpt (64..191), W2t (192..255), vector scatter (256..) ----
__global__ __launch_bounds__(256)
void prep(const float* __restrict__ W1, const float* __restrict__ Wp,
          const float* __restrict__ W2, const float* __restrict__ pos, int N,
          ushort* __restrict__ W1t, ushort* __restrict__ Wpt,
          ushort* __restrict__ W2t, float4* __restrict__ pos4s,
          int* __restrict__ origidx, int* __restrict__ cellcnt,
          int* __restrict__ ovfidx, float4* __restrict__ ovfpos) {
    const int b = blockIdx.x;
    if (b < 64) {
        __shared__ float tile[32][33];
        const int ti = b >> 3, tj = b & 7;
        const int r  = threadIdx.x >> 5, c = threadIdx.x & 31;
#pragma unroll
        for (int rr = r; rr < 32; rr += 8)
            tile[rr][c] = W1[(ti * 32 + rr) * H + tj * 32 + c];
        __syncthreads();
#pragma unroll
        for (int rr = r; rr < 32; rr += 8)
            W1t[(tj * 32 + rr) * H + ti * 32 + c] = f2bf(tile[c][rr]);
    } else if (b < 192) {
        __shared__ float tile[32][33];
        const int b2 = b - 64;
        const int ti = b2 >> 3, tj = b2 & 7;
        const int r  = threadIdx.x >> 5, c = threadIdx.x & 31;
#pragma unroll
        for (int rr = r; rr < 32; rr += 8)
            tile[rr][c] = Wp[(ti * 32 + rr) * H + tj * 32 + c];
        __syncthreads();
#pragma unroll
        for (int rr = r; rr < 32; rr += 8)
            Wpt[(tj * 32 + rr) * (2 * H) + ti * 32 + c] = f2bf(tile[c][rr]);
    } else if (b < 256) {
        __shared__ float tile[32][33];
        const int b2 = b - 192;
        const int ti = b2 >> 3, tj = b2 & 7;
        const int r  = threadIdx.x >> 5, c = threadIdx.x & 31;
#pragma unroll
        for (int rr = r; rr < 32; rr += 8)
            tile[rr][c] = W2[(ti * 32 + rr) * H + tj * 32 + c];
        __syncthreads();
#pragma unroll
        for (int rr = r; rr < 32; rr += 8)
            W2t[(tj * 32 + rr) * H + ti * 32 + c] = f2bf(tile[c][rr]);
    } else {
        const int sb = b - 256;
        const int base = sb * 1024;
        const int t = threadIdx.x;
        auto scat = [&](float x, float y, float z, int i) {
            float4 P = make_float4(x, y, z, 0.f);
            int c = cell_of(x, y, z);
            int slot = atomicAdd(&cellcnt[c], 1);
            if (slot < SLOTS) {
                pos4s[c * SLOTS + slot] = P;
                origidx[c * SLOTS + slot] = i;
            } else {
                int o = atomicAdd(&cellcnt[4096], 1);
                if (o < OCAP) { ovfpos[o] = P; ovfidx[o] = i; }
            }
        };
        if (base + 1024 <= N) {
            const float4* p4 = (const float4*)(pos + (size_t)base * 3);
            float4 f0 = p4[3 * t + 0];
            float4 f1 = p4[3 * t + 1];
            float4 f2 = p4[3 * t + 2];
            const int ib = base + 4 * t;
            scat(f0.x, f0.y, f0.z, ib + 0);
            scat(f0.w, f1.x, f1.y, ib + 1);
            scat(f1.z, f1.w, f2.x, ib + 2);
            scat(f2.y, f2.z, f2.w, ib + 3);
        } else {
            for (int i = base + t; i < N; i += 256)
                scat(pos[3 * i], pos[3 * i + 1], pos[3 * i + 2], i);
        }
    }
}

// ---- fused: select (cell-tau -> phase1 tau* -> phase2 -> top-32) ->
//      embed -> MFMA GEMM1 -> gelu/mean -> hbB (bf16); supE -> supEB ----
__global__ __launch_bounds__(TPB, 8)
void fused_knn_mlp(const float* __restrict__ pos,
                   const float4* __restrict__ pos4s,
                   const int* __restrict__ origidx,
                   const int* __restrict__ cellcnt,
                   const int* __restrict__ ovfidx, const float4* __restrict__ ovfpos,
                   const int* __restrict__ supidx,
                   const ushort* __restrict__ W1t, const float* __restrict__ b1,
                   ushort* __restrict__ supEB, ushort* __restrict__ hbB)
{
    __shared__ __align__(16) char pool[16384];
    float* amaxd = (float*)pool;
    int*   acnt  = (int*)(pool + 512);
    int*   ccell = (int*)(pool + 1024);
    int*   ccnt  = (int*)(pool + 2048);
    float* cmnd  = (float*)(pool + 3072);
    int*   cpre  = (int*)(pool + 4096);
    float* d2buf = (float*)(pool + 5120);
    int*   obuf  = (int*)(pool + 7168);
    float* pxb   = (float*)(pool + 9216);
    float* pyb   = (float*)(pool + 11264);
    float* pzb   = (float*)(pool + 13312);
    ushort* msg  = (ushort*)pool;

    __shared__ float rf[KNB][5];
    __shared__ int   selo[KNB];
    __shared__ int   wsum[4];
    __shared__ float tau2_sh, tau32_sh;
    __shared__ int   cnt_sh, ncl;

    const int s    = blockIdx.x;
    const int t    = threadIdx.x;
    const int lane = t & 63;
    const int w    = t >> 6;       // wave 0..7

    const int sidx = supidx[s];
    const float sx = pos[3 * sidx], sy = pos[3 * sidx + 1], sz = pos[3 * sidx + 2];

    constexpr float L2_10000 = 13.287712379549449f;

    if (t == 0) { ncl = 0; tau2_sh = 301.f; }

    // ---- stage A: issue cellcnt window loads FIRST (latency hidden by supE) ----
    const int scx = min(GC - 1, max(0, (int)(sx * HINV)));
    const int scy = min(GC - 1, max(0, (int)(sy * HINV)));
    const int scz = min(GC - 1, max(0, (int)(sz * HINV)));
    const int ax0 = max(0, scx - 2), ax1 = min(GC - 1, scx + 2);
    const int ay0 = max(0, scy - 2), ay1 = min(GC - 1, scy + 2);
    const int az0 = max(0, scz - 2), az1 = min(GC - 1, scz + 2);
    const int anx = ax1 - ax0 + 1, any_ = ay1 - ay0 + 1, anz = az1 - az0 + 1;
    const int an  = anx * any_ * anz;    // <= 125
    if (t < an) {
        int ci = t;
        int X = ax0 + ci % anx, rem = ci / anx;
        int Y = ay0 + rem % any_, Z = az0 + rem / any_;
        int cell = (Z * GC + Y) * GC + X;
        acnt[ci] = min(cellcnt[cell], SLOTS);
        float lx = X * HCEL, ly = Y * HCEL, lz = Z * HCEL;
        float mx = fmaxf(fabsf(sx - lx), fabsf(lx + HCEL - sx));
        float my = fmaxf(fabsf(sy - ly), fabsf(ly + HCEL - sy));
        float mz = fmaxf(fabsf(sz - lz), fabsf(lz + HCEL - sz));
        amaxd[ci] = mx * mx + my * my + mz * mz;
    }

    // supE embed -> supEB[s][0..255] (bf16), overlapping the loads above
    if (t < 256) {
        float se = 0.f;
        if (t < 252) {
            int c  = t / 84;
            int rr = t - c * 84;
            int f  = (rr < 42) ? rr : rr - 42;
            float coord = (c == 0) ? sx : ((c == 1) ? sy : sz);
            float ang = coord * exp2f(-(float)f * (L2_10000 / 42.f));
            se = (rr < 42) ? __sinf(ang) : __cosf(ang);
        }
        supEB[s * H + t] = f2bf(se);
    }
    __syncthreads();
    if (t < an) {
        int ci = t;
        float myv = amaxd[ci];
        int Sc = 0;
        for (int j = 0; j < an; j++) {
            bool less = (amaxd[j] < myv) || (amaxd[j] == myv && j < ci);
            Sc += less ? acnt[j] : 0;
        }
        if (Sc < KNB && KNB <= Sc + acnt[ci]) tau2_sh = myv;
    }
    __syncthreads();
    const float tau2 = tau2_sh;
    const float R2 = tau2 + 1e-3f;
    const float R  = sqrtf(R2);
    if (t == 0) tau32_sh = R2;   // fallback if phase1 < 32

    // ---- stage B: build ball-cell list (cell, cnt|p1flag, mind2) ----
    const int bx0 = max(0, (int)floorf((sx - R) * HINV));
    const int bx1 = min(GC - 1, (int)floorf((sx + R) * HINV));
    const int by0 = max(0, (int)floorf((sy - R) * HINV));
    const int by1 = min(GC - 1, (int)floorf((sy + R) * HINV));
    const int bz0 = max(0, (int)floorf((sz - R) * HINV));
    const int bz1 = min(GC - 1, (int)floorf((sz + R) * HINV));
    const bool inwin = (bx0 >= ax0 && bx1 <= ax1 && by0 >= ay0 && by1 <= ay1 &&
                        bz0 >= az0 && bz1 <= az1);
    if (inwin) {
        if (t < an) {
            int ci = t;
            int cn = acnt[ci];
            if (cn > 0) {
                int X = ax0 + ci % anx, rem = ci / anx;
                int Y = ay0 + rem % any_, Z = az0 + rem / any_;
                float lx = X * HCEL, ly = Y * HCEL, lz = Z * HCEL;
                float ddx = fmaxf(fmaxf(lx - sx, sx - (lx + HCEL)), 0.f);
                float ddy = fmaxf(fmaxf(ly - sy, sy - (ly + HCEL)), 0.f);
                float ddz = fmaxf(fmaxf(lz - sz, sz - (lz + HCEL)), 0.f);
                float mnd = ddx * ddx + ddy * ddy + ddz * ddz;
                if (mnd <= R2) {
                    int p1 = (amaxd[ci] <= tau2) ? 1 : 0;
                    int cell = (Z * GC + Y) * GC + X;
                    int sl = atomicAdd(&ncl, 1);
                    if (sl < 256) { ccell[sl] = cell; ccnt[sl] = cn | (p1 << 8); cmnd[sl] = mnd; }
                }
            }
        }
    } else {
        const int nbx = bx1 - bx0 + 1, nby = by1 - by0 + 1, nbz = bz1 - bz0 + 1;
        const int ncb = nbx * nby * nbz;
        for (int ci = t; ci < ncb; ci += TPB) {
            int X = bx0 + ci % nbx, rem = ci / nbx;
            int Y = by0 + rem % nby, Z = bz0 + rem / nby;
            float lx = X * HCEL, ly = Y * HCEL, lz = Z * HCEL;
            float ddx = fmaxf(fmaxf(lx - sx, sx - (lx + HCEL)), 0.f);
            float ddy = fmaxf(fmaxf(ly - sy, sy - (ly + HCEL)), 0.f);
            float ddz = fmaxf(fmaxf(lz - sz, sz - (lz + HCEL)), 0.f);
            float mnd = ddx * ddx + ddy * ddy + ddz * ddz;
            if (mnd > R2) continue;
            int cell = (Z * GC + Y) * GC + X;
            int cn = min(cellcnt[cell], SLOTS);
            if (cn == 0) continue;
            float mx = fmaxf(fabsf(sx - lx), fabsf(lx + HCEL - sx));
            float my = fmaxf(fabsf(sy - ly), fabsf(ly + HCEL - sy));
            float mz = fmaxf(fabsf(sz - lz), fabsf(lz + HCEL - sz));
            float amx = mx * mx + my * my + mz * mz;
            int p1 = (amx <= tau2) ? 1 : 0;
            int sl = atomicAdd(&ncl, 1);
            if (sl < 256) { ccell[sl] = cell; ccnt[sl] = cn | (p1 << 8); cmnd[sl] = mnd; }
        }
    }
    __syncthreads();
    const int nclc = min(ncl, 256);

    auto build_prefix = [&](int phase, float tlim) -> int {
        int v = 0;
        if (t < 256) {
            if (t < nclc) {
                int cc = ccnt[t];
                int cn = cc & 0xff;
                int p1 = cc >> 8;
                v = (phase == 1) ? (p1 ? cn : 0)
                                 : ((!p1 && cmnd[t] <= tlim) ? cn : 0);
            }
#pragma unroll
            for (int off = 1; off < 64; off <<= 1) {
                int x = __shfl_up(v, off);
                if (lane >= off) v += x;
            }
            if (lane == 63) wsum[w] = v;
        }
        __syncthreads();
        if (t < 256) {
            int add = 0;
#pragma unroll
            for (int j = 0; j < 4; j++) if (j < w) add += wsum[j];
            cpre[t] = v + add;
        }
        __syncthreads();
        return cpre[255];
    };
    auto bsearch = [&](int j) -> int {
        int lo = 0;
#pragma unroll
        for (int st = 128; st; st >>= 1) {
            int nlo = lo + st;
            if (nlo <= 256 && cpre[nlo - 1] <= j) lo = nlo;
        }
        return lo;
    };

    // ---- phase 1: gather ALL points of P1 cells (dense, no atomics) ----
    const int tot1 = build_prefix(1, 0.f);
    const int M1 = min(tot1, CAP);
    if (t < M1) {
        int j = t;
        int lo = bsearch(j);
        int off = j - (lo ? cpre[lo - 1] : 0);
        int u = ccell[lo] * SLOTS + off;
        float4 P = pos4s[u];
        float dx = sx - P.x, dy = sy - P.y, dz = sz - P.z;
        d2buf[j] = dx * dx + dy * dy + dz * dz;
        obuf[j]  = origidx[u];
        pxb[j] = P.x; pyb[j] = P.y; pzb[j] = P.z;
    }
    const int Mp1 = (M1 + 3) & ~3;
    if (M1 + t < Mp1) { d2buf[M1 + t] = INFINITY; obuf[M1 + t] = 0x7fffffff; }
    if (t == 0) cnt_sh = M1;
    __syncthreads();

    // exact 32nd-smallest of phase-1 set -> tau* (<= tau2 by construction)
    if (t < M1) {
        int u = t;
        float myv = d2buf[u];
        int   myo = obuf[u];
        int rank = 0;
        for (int v2 = 0; v2 < Mp1; v2 += 4) {
            float4 dv = *(const float4*)&d2buf[v2];
            int4   iv = *(const int4*)&obuf[v2];
            rank += (dv.x < myv) || (dv.x == myv && iv.x < myo);
            rank += (dv.y < myv) || (dv.y == myv && iv.y < myo);
            rank += (dv.z < myv) || (dv.z == myv && iv.z < myo);
            rank += (dv.w < myv) || (dv.w == myv && iv.w < myo);
        }
        if (rank == KNB - 1) tau32_sh = myv;
    }
    __syncthreads();
    const float tau32 = tau32_sh;

    // ---- phase 2: cells with mind2 <= tau*, filter d2 <= tau* (ballot append) ----
    const int tot2 = build_prefix(2, tau32);
    for (int j0 = 0; j0 < tot2; j0 += TPB) {
        int j = j0 + t;
        bool pass = false; float pd2 = 0.f; int po = 0; float qx = 0, qy = 0, qz = 0;
        if (j < tot2) {
            int lo = bsearch(j);
            int off = j - (lo ? cpre[lo - 1] : 0);
            int u = ccell[lo] * SLOTS + off;
            float4 P = pos4s[u];
            float dx = sx - P.x, dy = sy - P.y, dz = sz - P.z;
            pd2 = dx * dx + dy * dy + dz * dz;
            if (pd2 <= tau32) { pass = true; po = origidx[u]; qx = P.x; qy = P.y; qz = P.z; }
        }
        unsigned long long m = __ballot(pass);
        if (m) {
            int ldr = __ffsll(m) - 1;
            int base = 0;
            if (lane == ldr) base = atomicAdd(&cnt_sh, __popcll(m));
            base = __shfl(base, ldr);
            if (pass) {
                int slp = base + __popcll(m & ((1ull << lane) - 1ull));
                if (slp < CAP) {
                    d2buf[slp] = pd2; obuf[slp] = po;
                    pxb[slp] = qx; pyb[slp] = qy; pzb[slp] = qz;
                }
            }
        }
    }
    {
        int no = min(cellcnt[4096], OCAP);
        for (int j = t; j < no; j += TPB) {
            float4 P = ovfpos[j];
            float dx = sx - P.x, dy = sy - P.y, dz = sz - P.z;
            float pd2 = dx * dx + dy * dy + dz * dz;
            if (pd2 <= tau32) {
                int slp = atomicAdd(&cnt_sh, 1);
                if (slp < CAP) {
                    d2buf[slp] = pd2; obuf[slp] = ovfidx[j];
                    pxb[slp] = P.x; pyb[slp] = P.y; pzb[slp] = P.z;
                }
            }
        }
    }
    __syncthreads();
    const int M = min(cnt_sh, CAP);
    const int Mpad = (M + 3) & ~3;
    if (M + t < Mpad) { d2buf[M + t] = INFINITY; obuf[M + t] = 0x7fffffff; }
    __syncthreads();

    // ---- final exact rank-merge -> top-32 (store winning SLOT) ----
    if (t < M) {
        int u = t;
        float myv = d2buf[u];
        int   myo = obuf[u];
        int rank = 0;
        for (int v2 = 0; v2 < Mpad; v2 += 4) {
            float4 dv = *(const float4*)&d2buf[v2];
            int4   iv = *(const int4*)&obuf[v2];
            rank += (dv.x < myv) || (dv.x == myv && iv.x < myo);
            rank += (dv.y < myv) || (dv.y == myv && iv.y < myo);
            rank += (dv.z < myv) || (dv.z == myv && iv.z < myo);
            rank += (dv.w < myv) || (dv.w == myv && iv.w < myo);
        }
        if (rank < KNB) selo[rank] = u;
    }
    __syncthreads();
    if (t < KNB) {
        int u = selo[t];
        float rx = sx - pxb[u], ry = sy - pyb[u], rz = sz - pzb[u];
        float dd = sqrtf(d2buf[u]);
        rf[t][0] = rx; rf[t][1] = ry; rf[t][2] = rz; rf[t][3] = dd;
    }
    __syncthreads();   // select stage dead; msg takes pool

    // ---- sincos embed -> msg[k][i] bf16, row-XOR swizzle ----
#pragma unroll
    for (int n = 0; n < 8; n++) {
        int item = t + n * TPB;
        int f = item & 31;
        int c = (item >> 5) & 3;
        int k = item >> 7;
        float ang = rf[k][c] * exp2f(-(float)f * (L2_10000 / 32.f));
        int swz = (k & 7) << 3;
        msg[((k << 8) | (c * 64 + f))      ^ swz] = f2bf(__sinf(ang));
        msg[((k << 8) | (c * 64 + 32 + f)) ^ swz] = f2bf(__cosf(ang));
    }
    __syncthreads();

    // ---- MFMA GEMM1: wave w owns j-rows [32w, 32w+32); epilogue -> hbB bf16 ----
    {
        const int lr = lane & 15;
        const int lg = lane >> 4;
        f32x4 acc00 = {0,0,0,0}, acc01 = {0,0,0,0};
        f32x4 acc10 = {0,0,0,0}, acc11 = {0,0,0,0};
#pragma unroll
        for (int kk = 0; kk < 8; kk++) {
            const int i0 = kk * 32 + lg * 8;
            bf16x8 a0 = *(const bf16x8*)(W1t + ((32 * w      + lr) << 8) + i0);
            bf16x8 a1 = *(const bf16x8*)(W1t + ((32 * w + 16 + lr) << 8) + i0);
            const int swz = (lr & 7) << 3;
            bf16x8 b0  = *(const bf16x8*)(msg + ((( lr       << 8) | i0) ^ swz));
            bf16x8 b1v = *(const bf16x8*)(msg + ((((lr + 16) << 8) | i0) ^ swz));
            acc00 = __builtin_amdgcn_mfma_f32_16x16x32_bf16(a0, b0,  acc00, 0, 0, 0);
            acc01 = __builtin_amdgcn_mfma_f32_16x16x32_bf16(a0, b1v, acc01, 0, 0, 0);
            acc10 = __builtin_amdgcn_mfma_f32_16x16x32_bf16(a1, b0,  acc10, 0, 0, 0);
            acc11 = __builtin_amdgcn_mfma_f32_16x16x32_bf16(a1, b1v, acc11, 0, 0, 0);
        }
        float part[8];
#pragma unroll
        for (int mm = 0; mm < 2; mm++)
#pragma unroll
            for (int r = 0; r < 4; r++) {
                int j = 32 * w + 16 * mm + 4 * lg + r;
                float bj = b1[j];
                float h0 = (mm == 0 ? acc00[r] : acc10[r]) + bj;
                float h1 = (mm == 0 ? acc01[r] : acc11[r]) + bj;
                part[mm * 4 + r] = gelu_fast(h0) + gelu_fast(h1);
            }
#pragma unroll
        for (int off = 1; off < 16; off <<= 1)
#pragma unroll
            for (int u = 0; u < 8; u++)
                part[u] += __shfl_xor(part[u], off);
        if (lr == 0) {
#pragma unroll
            for (int u = 0; u < 8; u++) {
                int mm = u >> 2, r = u & 3;
                hbB[s * H + 32 * w + 16 * mm + 4 * lg + r] = f2bf(part[u] * (1.0f / 32.0f));
            }
        }
    }
}

// ---- mfma_out2: 64 blocks x 512; 16 s-rows each.
//  stage1: agg[j][s] = sum_i W2t[j][i]*hbB[s][i] + b2  -> swizzled LDS bf16
//  stage2: out[s][jo] = sum_io Wpt[jo][io]*feats[s][io] + bp ----
__global__ __launch_bounds__(512)
void mfma_out2(const ushort* __restrict__ hbB, const ushort* __restrict__ supEB,
               const ushort* __restrict__ W2t, const float* __restrict__ b2,
               const ushort* __restrict__ Wpt, const float* __restrict__ bp,
               float* __restrict__ out)
{
    __shared__ ushort agg[16 * 256];   // [s_local][j], row-XOR swizzled
    const int bm   = blockIdx.x;
    const int t    = threadIdx.x;
    const int lane = t & 63;
    const int w    = t >> 6;
    const int lr   = lane & 15;
    const int lg   = lane >> 4;

    // stage 1
    f32x4 acc1[2] = {{0,0,0,0},{0,0,0,0}};
#pragma unroll
    for (int kk = 0; kk < 8; kk++) {
        const int i0 = kk * 32 + lg * 8;
        bf16x8 bf = *(const bf16x8*)(hbB + (16 * bm + lr) * H + i0);
        bf16x8 a0 = *(const bf16x8*)(W2t + ((32 * w      + lr) << 8) + i0);
        bf16x8 a1 = *(const bf16x8*)(W2t + ((32 * w + 16 + lr) << 8) + i0);
        acc1[0] = __builtin_amdgcn_mfma_f32_16x16x32_bf16(a0, bf, acc1[0], 0, 0, 0);
        acc1[1] = __builtin_amdgcn_mfma_f32_16x16x32_bf16(a1, bf, acc1[1], 0, 0, 0);
    }
#pragma unroll
    for (int mt = 0; mt < 2; mt++)
#pragma unroll
        for (int r = 0; r < 4; r++) {
            int j = 32 * w + 16 * mt + 4 * lg + r;
            int sl = lane & 15;
            float v = acc1[mt][r] + b2[j];
            agg[((sl << 8) | j) ^ ((sl & 7) << 3)] = f2bf(v);
        }
    __syncthreads();

    // stage 2
    f32x4 acc2[2] = {{0,0,0,0},{0,0,0,0}};
#pragma unroll
    for (int kk = 0; kk < 16; kk++) {
        const int io = kk * 32 + lg * 8;
        bf16x8 bf;
        if (kk < 8) {
            bf = *(const bf16x8*)(supEB + (16 * bm + lr) * H + io);
        } else {
            int c = io - 256;
            bf = *(const bf16x8*)(agg + (((lr << 8) | c) ^ ((lr & 7) << 3)));
        }
        bf16x8 a0 = *(const bf16x8*)(Wpt + (32 * w      + lr) * 512 + io);
        bf16x8 a1 = *(const bf16x8*)(Wpt + (32 * w + 16 + lr) * 512 + io);
        acc2[0] = __builtin_amdgcn_mfma_f32_16x16x32_bf16(a0, bf, acc2[0], 0, 0, 0);
        acc2[1] = __builtin_amdgcn_mfma_f32_16x16x32_bf16(a1, bf, acc2[1], 0, 0, 0);
    }
#pragma unroll
    for (int mt = 0; mt < 2; mt++)
#pragma unroll
        for (int r = 0; r < 4; r++) {
            int jo = 32 * w + 16 * mt + 4 * lg + r;
            int srow = 16 * bm + (lane & 15);
            out[srow * H + jo] = acc2[mt][r] + bp[jo];
        }
}

extern "C" void kernel_launch(void* const* d_in, const int* in_sizes, int n_in,
                              void* d_out, int out_size, void* d_ws, size_t ws_size,
                              hipStream_t stream) {
    const float* pos = (const float*)d_in[0];
    const int*   sup = (const int*)d_in[1];
    const float* W1  = (const float*)d_in[2];
    const float* b1  = (const float*)d_in[3];
    const float* W2  = (const float*)d_in[4];
    const float* b2  = (const float*)d_in[5];
    const float* Wp  = (const float*)d_in[6];
    const float* bp  = (const float*)d_in[7];

    const int N = in_sizes[0] / 3;
    const int S = in_sizes[1];
    float* out = (float*)d_out;

    char* ws = (char*)d_ws;
    ushort* W1t     = (ushort*)ws;                      // 128 KB
    ushort* Wpt     = (ushort*)(ws + (128 << 10));      // 256 KB bf16 [256][512]
    ushort* W2t     = (ushort*)(ws + (384 << 10));      // 128 KB bf16 [256][256]
    float4* pos4s   = (float4*)(ws + (512 << 10));      // 2 MB
    int*    origidx = (int*)(ws + (2560 << 10));        // 512 KB
    int*    cellcnt = (int*)(ws + (3072 << 10));        // 4097 ints
    int*    ovfidx  = (int*)(ws + (3092 << 10));        // 1 KB
    float4* ovfpos  = (float4*)(ws + (3096 << 10));     // 4 KB
    ushort* supEB   = (ushort*)(ws + (3104 << 10));     // 512 KB bf16 [S][256]
    ushort* hbB     = (ushort*)(ws + (3616 << 10));     // 512 KB bf16 [S][256]

    hipMemsetAsync(cellcnt, 0, 4097 * sizeof(int), stream);
    const int nscat = (N + 1023) / 1024;
    prep<<<256 + nscat, 256, 0, stream>>>(W1, Wp, W2, pos, N,
                                          W1t, Wpt, W2t, pos4s,
                                          origidx, cellcnt, ovfidx, ovfpos);
    fused_knn_mlp<<<S, TPB, 0, stream>>>(pos, pos4s, origidx, cellcnt,
                                         ovfidx, ovfpos, sup,
                                         W1t, b1, supEB, hbB);
    mfma_out2<<<S / 16, 512, 0, stream>>>(hbB, supEB, W2t, b2, Wpt, bp, out);
}